// Round 6
// baseline (405.476 us; speedup 1.0000x reference)
//
#include <hip/hip_runtime.h>

// GCN 2-layer forward, CSR-gather formulation. All fp32.
// out[d] = dinv[d] * ( sum_{e: src->d} g[src] + g[d] ) + bias,
// where g[i] = (h W)[i] * dinv[i]; self-loop is the +g[d] term.
// CSR built via binned partition with NO global atomics and NO memsets:
//   k_bhist:   per-(block,bucket) histogram, plain coalesced stores
//   k_colscan: column-sum -> bucket totals -> exclusive scan -> bucket_base;
//              rewrite hist into exact per-(block,bucket) write bases
//   k_bin:     scatter (src,dst) into bucket regions (LDS cursors seeded
//              from hist; deterministic layout)
//   k_place:   per-bucket -> per-node counts/scan in LDS, emit row_start/
//              cnt/dinv and csr with LDS cursors.

#define BKT_SHIFT 8            // 256 nodes per bucket
#define BIN_EPT 16             // edges per thread in binning kernels (4096/block)

// Per-block bucket histogram of dst. hist[bl*NB + b] fully written.
__global__ __launch_bounds__(256) void k_bhist(
    const int* __restrict__ dst, int* __restrict__ hist, int E, int NB) {
    extern __shared__ int h[];  // NB ints
    const int t = threadIdx.x;
    const int base = blockIdx.x * (256 * BIN_EPT);
    for (int b = t; b < NB; b += 256) h[b] = 0;
    __syncthreads();
#pragma unroll
    for (int j = 0; j < BIN_EPT; ++j) {
        int e = base + j * 256 + t;
        if (e < E) atomicAdd(&h[dst[e] >> BKT_SHIFT], 1);
    }
    __syncthreads();
    for (int b = t; b < NB; b += 256)
        hist[(size_t)blockIdx.x * NB + b] = h[b];
}

// One block: bucket totals (column sums of hist), exclusive scan ->
// bucket_base, then rewrite hist columns into per-block write bases.
__global__ __launch_bounds__(512) void k_colscan(
    int* __restrict__ hist, int* __restrict__ bucket_base, int NBL, int NB) {
    __shared__ int lds[512];
    const int t = threadIdx.x;
    int total = 0;
    if (t < NB) {
#pragma unroll 4
        for (int bl = 0; bl < NBL; ++bl) total += hist[(size_t)bl * NB + t];
    }
    lds[t] = (t < NB) ? total : 0;
    __syncthreads();
    for (int off = 1; off < 512; off <<= 1) {
        int u = (t >= off) ? lds[t - off] : 0;
        __syncthreads();
        lds[t] += u;
        __syncthreads();
    }
    if (t < NB) {
        int run = lds[t] - total;  // exclusive prefix = bucket base
        bucket_base[t] = run;
#pragma unroll 4
        for (int bl = 0; bl < NBL; ++bl) {
            size_t idx = (size_t)bl * NB + t;
            int c = hist[idx];
            hist[idx] = run;
            run += c;
        }
    }
}

// Bin (src,dst) pairs into per-bucket regions of `binned`. LDS cursors are
// seeded with this block's exact global bases -> no global atomics.
__global__ __launch_bounds__(256) void k_bin(
    const int* __restrict__ src, const int* __restrict__ dst,
    const int* __restrict__ hist, int2* __restrict__ binned, int E, int NB) {
    extern __shared__ int lds_pos[];  // NB ints
    const int t = threadIdx.x;
    const int base = blockIdx.x * (256 * BIN_EPT);
    for (int b = t; b < NB; b += 256)
        lds_pos[b] = hist[(size_t)blockIdx.x * NB + b];
    __syncthreads();
#pragma unroll
    for (int j = 0; j < BIN_EPT; ++j) {
        int e = base + j * 256 + t;
        if (e < E) {
            int s = src[e], d = dst[e];
            int pos = atomicAdd(&lds_pos[d >> BKT_SHIFT], 1);
            binned[pos] = make_int2(s, d);
        }
    }
}

// One block per bucket: per-node degree count in LDS, LDS scan ->
// row_start/cnt/dinv, then place csr with LDS cursors.
__global__ __launch_bounds__(256) void k_place(
    const int2* __restrict__ binned, const int* __restrict__ bucket_base,
    int* __restrict__ row_start, int* __restrict__ cnt, float* __restrict__ dinv,
    int* __restrict__ csr, int E, int n, int NB) {
    __shared__ int lcnt[256], sc[256];
    const int b = blockIdx.x;
    const int t = threadIdx.x;
    const int lo = bucket_base[b];
    const int hi = (b + 1 < NB) ? bucket_base[b + 1] : E;
    lcnt[t] = 0;
    __syncthreads();
    for (int i = lo + t; i < hi; i += 256)
        atomicAdd(&lcnt[binned[i].y & 255], 1);
    __syncthreads();
    int c = lcnt[t];
    sc[t] = c;
    __syncthreads();
    for (int off = 1; off < 256; off <<= 1) {
        int u = (t >= off) ? sc[t - off] : 0;
        __syncthreads();
        sc[t] += u;
        __syncthreads();
    }
    int excl = sc[t] - c;
    const int node = (b << BKT_SHIFT) + t;
    if (node < n) {
        row_start[node] = lo + excl;
        cnt[node] = c;
        dinv[node] = rsqrtf((float)c + 1.0f);
    }
    lcnt[t] = excl;  // becomes the local cursor
    __syncthreads();
    for (int i = lo + t; i < hi; i += 256) {
        int2 p = binned[i];
        int r = atomicAdd(&lcnt[p.y & 255], 1);
        csr[lo + r] = p.x;
    }
}

// g1[row][o] = (x[row] @ W1)[o] * dinv[row]
// wave-per-row: lane l covers k in {4l..4l+3} u {256+4l..256+4l+3},
// W fragment in registers, reduce-scatter via shfl_xor.
__global__ __launch_bounds__(256) void k_gemm1(
    const float* __restrict__ x, const float* __restrict__ W1,
    const float* __restrict__ dinv, float* __restrict__ g1, int n) {
    const int lane = threadIdx.x & 63;
    const int wid  = blockIdx.x * (blockDim.x >> 6) + (threadIdx.x >> 6);
    const int nw   = gridDim.x * (blockDim.x >> 6);
    const float4* __restrict__ xv = (const float4*)x;
    const float4* __restrict__ wv = (const float4*)W1;

    float wreg[8][16];
#pragma unroll
    for (int j = 0; j < 4; ++j) {
#pragma unroll
        for (int q = 0; q < 4; ++q) {
            float4 wa = wv[(4 * lane + j) * 4 + q];
            wreg[j][4 * q + 0] = wa.x; wreg[j][4 * q + 1] = wa.y;
            wreg[j][4 * q + 2] = wa.z; wreg[j][4 * q + 3] = wa.w;
            float4 wb = wv[(256 + 4 * lane + j) * 4 + q];
            wreg[4 + j][4 * q + 0] = wb.x; wreg[4 + j][4 * q + 1] = wb.y;
            wreg[4 + j][4 * q + 2] = wb.z; wreg[4 + j][4 * q + 3] = wb.w;
        }
    }

    int row = wid;
    float4 a = make_float4(0.f, 0.f, 0.f, 0.f), b = a;
    if (row < n) { a = xv[row * 128 + lane]; b = xv[row * 128 + 64 + lane]; }
    for (; row < n; row += nw) {
        int nrow = row + nw;
        float4 a2 = a, b2 = b;
        if (nrow < n) { a2 = xv[nrow * 128 + lane]; b2 = xv[nrow * 128 + 64 + lane]; }

        float av[8] = {a.x, a.y, a.z, a.w, b.x, b.y, b.z, b.w};
        float acc[16];
#pragma unroll
        for (int o = 0; o < 16; ++o) acc[o] = 0.f;
#pragma unroll
        for (int j = 0; j < 8; ++j)
#pragma unroll
            for (int o = 0; o < 16; ++o) acc[o] = fmaf(av[j], wreg[j][o], acc[o]);

#pragma unroll
        for (int i = 0; i < 8; ++i) {
            float send = (lane & 32) ? acc[i] : acc[i + 8];
            float recv = __shfl_xor(send, 32);
            float keep = (lane & 32) ? acc[i + 8] : acc[i];
            acc[i] = keep + recv;
        }
#pragma unroll
        for (int i = 0; i < 4; ++i) {
            float send = (lane & 16) ? acc[i] : acc[i + 4];
            float recv = __shfl_xor(send, 16);
            float keep = (lane & 16) ? acc[i + 4] : acc[i];
            acc[i] = keep + recv;
        }
#pragma unroll
        for (int i = 0; i < 2; ++i) {
            float send = (lane & 8) ? acc[i] : acc[i + 2];
            float recv = __shfl_xor(send, 8);
            float keep = (lane & 8) ? acc[i + 2] : acc[i];
            acc[i] = keep + recv;
        }
        {
            float send = (lane & 4) ? acc[0] : acc[1];
            float recv = __shfl_xor(send, 4);
            float keep = (lane & 4) ? acc[1] : acc[0];
            acc[0] = keep + recv;
        }
        float r = acc[0];
        r += __shfl_xor(r, 1);
        r += __shfl_xor(r, 2);
        if ((lane & 3) == 0) g1[(size_t)row * 16 + (lane >> 2)] = r * dinv[row];
        a = a2; b = b2;
    }
}

// Wave per node: gather-sum g1 over CSR neighbors, fuse h2=relu(...), h3=h2@W2,
// g2 = h3*dinv. Lane layout: lane = eo*16 + f (4 edge slots x 16 features).
__global__ __launch_bounds__(256) void k_gather1(
    const int* __restrict__ row_start, const int* __restrict__ cnt,
    const int* __restrict__ csr, const float* __restrict__ g1,
    const float* __restrict__ dinv, const float* __restrict__ W2,
    const float* __restrict__ b1, float* __restrict__ g2, int n) {
    const int wid = blockIdx.x * 4 + (threadIdx.x >> 6);
    if (wid >= n) return;
    const int lane = threadIdx.x & 63;
    const int f = lane & 15, eo = lane >> 4;
    const int base = row_start[wid], deg = cnt[wid];
    float acc = 0.f;
    for (int j = eo; j < deg; j += 4) {
        int s = csr[base + j];
        acc += g1[(size_t)s * 16 + f];
    }
    acc += __shfl_xor(acc, 16);
    acc += __shfl_xor(acc, 32);
    const float dv = dinv[wid];
    float h2 = fmaxf(fmaf(dv, acc + g1[(size_t)wid * 16 + f], b1[f]), 0.f);
    float p0 = h2 * W2[2 * f], p1 = h2 * W2[2 * f + 1];
#pragma unroll
    for (int m = 1; m < 16; m <<= 1) {
        p0 += __shfl_xor(p0, m);
        p1 += __shfl_xor(p1, m);
    }
    if (lane == 0) ((float2*)g2)[wid] = make_float2(p0 * dv, p1 * dv);
}

// Wave per node: gather-sum float2 g2 over CSR neighbors, fuse bias -> out.
__global__ __launch_bounds__(256) void k_gather2(
    const int* __restrict__ row_start, const int* __restrict__ cnt,
    const int* __restrict__ csr, const float* __restrict__ g2,
    const float* __restrict__ dinv, const float* __restrict__ b2,
    float* __restrict__ out, int n) {
    const int wid = blockIdx.x * 4 + (threadIdx.x >> 6);
    if (wid >= n) return;
    const int lane = threadIdx.x & 63;
    const int base = row_start[wid], deg = cnt[wid];
    float a0 = 0.f, a1 = 0.f;
    for (int j = lane; j < deg; j += 64) {
        int s = csr[base + j];
        float2 v = ((const float2*)g2)[s];
        a0 += v.x; a1 += v.y;
    }
#pragma unroll
    for (int m = 1; m < 64; m <<= 1) {
        a0 += __shfl_xor(a0, m);
        a1 += __shfl_xor(a1, m);
    }
    if (lane == 0) {
        float dv = dinv[wid];
        float2 g = ((const float2*)g2)[wid];
        ((float2*)out)[wid] = make_float2(fmaf(dv, a0 + g.x, b2[0]),
                                          fmaf(dv, a1 + g.y, b2[1]));
    }
}

extern "C" void kernel_launch(void* const* d_in, const int* in_sizes, int n_in,
                              void* d_out, int out_size, void* d_ws, size_t ws_size,
                              hipStream_t stream) {
    const float* x  = (const float*)d_in[0];
    const int*   ei = (const int*)d_in[1];
    const float* W1 = (const float*)d_in[2];
    const float* b1 = (const float*)d_in[3];
    const float* W2 = (const float*)d_in[4];
    const float* b2 = (const float*)d_in[5];
    float* out = (float*)d_out;

    const int n = in_sizes[0] / 512;
    const int E = in_sizes[1] / 2;
    const int* src = ei;
    const int* dst = ei + E;

    const int NB = (n + (1 << BKT_SHIFT) - 1) >> BKT_SHIFT;      // buckets (<=512)
    const int nb_bin = (E + 256 * BIN_EPT - 1) / (256 * BIN_EPT); // bin blocks

    char* ws = (char*)d_ws;
    size_t off = 0;
    auto alloc = [&](size_t bytes) {
        char* p = ws + off;
        off += (bytes + 255) & ~(size_t)255;
        return p;
    };
    float* dinv      = (float*)alloc((size_t)n * 4);
    float* g1        = (float*)alloc((size_t)n * 16 * 4);
    float* g2        = (float*)alloc((size_t)n * 2 * 4);
    int*   cnt       = (int*)alloc((size_t)n * 4);
    int*   row_start = (int*)alloc((size_t)n * 4);
    int*   csr       = (int*)alloc((size_t)E * 4);
    int2*  binned    = (int2*)alloc((size_t)E * 8);
    int*   hist        = (int*)alloc((size_t)nb_bin * NB * 4);
    int*   bucket_base = (int*)alloc((size_t)NB * 4);

    const int nb_w = (n + 3) / 4;  // wave-per-node kernels, 4 waves/block

    k_bhist<<<nb_bin, 256, NB * 4, stream>>>(dst, hist, E, NB);
    k_colscan<<<1, 512, 0, stream>>>(hist, bucket_base, nb_bin, NB);
    k_bin<<<nb_bin, 256, NB * 4, stream>>>(src, dst, hist, binned, E, NB);
    k_place<<<NB, 256, 0, stream>>>(binned, bucket_base, row_start, cnt, dinv, csr, E, n, NB);
    k_gemm1<<<1024, 256, 0, stream>>>(x, W1, dinv, g1, n);
    k_gather1<<<nb_w, 256, 0, stream>>>(row_start, cnt, csr, g1, dinv, W2, b1, g2, n);
    k_gather2<<<nb_w, 256, 0, stream>>>(row_start, cnt, csr, g2, dinv, b2, out, n);
}

// Round 7
// 313.152 us; speedup vs baseline: 1.2948x; 1.2948x over previous
//
#include <hip/hip_runtime.h>

// GCN 2-layer forward, CSR-gather formulation. All fp32.
// out[d] = dinv[d] * ( sum_{e: src->d} g[src] + g[d] ) + bias,
// where g[i] = (h W)[i] * dinv[i]; self-loop is the +g[d] term.
// CSR built via binned partition with NO global atomics and NO memsets:
//   k_bhist:  per-(block,bucket) histogram, plain coalesced stores
//   k_colsum: wave-per-bucket column sums -> bucket_total
//   k_scan_nb: scan bucket totals -> bucket_base (1 small block)
//   k_rebase: wave-per-bucket chunked shuffle-scan down each column ->
//             exact per-(block,bucket) write bases in hist
//   k_bin:    scatter (src,dst) into bucket regions (LDS cursors seeded
//             from hist; deterministic layout)
//   k_place:  per-bucket -> per-node counts/scan in LDS, emit row_start/
//             cnt/dinv and csr with LDS cursors.

#define BKT_SHIFT 8            // 256 nodes per bucket
#define BIN_EPT 16             // edges per thread in binning kernels (4096/block)

// Per-block bucket histogram of dst. hist[bl*NB + b] fully written.
__global__ __launch_bounds__(256) void k_bhist(
    const int* __restrict__ dst, int* __restrict__ hist, int E, int NB) {
    extern __shared__ int h[];  // NB ints
    const int t = threadIdx.x;
    const int base = blockIdx.x * (256 * BIN_EPT);
    for (int b = t; b < NB; b += 256) h[b] = 0;
    __syncthreads();
#pragma unroll
    for (int j = 0; j < BIN_EPT; ++j) {
        int e = base + j * 256 + t;
        if (e < E) atomicAdd(&h[dst[e] >> BKT_SHIFT], 1);
    }
    __syncthreads();
    for (int b = t; b < NB; b += 256)
        hist[(size_t)blockIdx.x * NB + b] = h[b];
}

// Wave per bucket: column sum of hist -> bucket_total.
__global__ __launch_bounds__(256) void k_colsum(
    const int* __restrict__ hist, int* __restrict__ bucket_total,
    int NBL, int NB) {
    const int b = blockIdx.x * 4 + (threadIdx.x >> 6);
    if (b >= NB) return;
    const int lane = threadIdx.x & 63;
    int s = 0;
    for (int bl = lane; bl < NBL; bl += 64) s += hist[(size_t)bl * NB + b];
#pragma unroll
    for (int m = 1; m < 64; m <<= 1) s += __shfl_xor(s, m);
    if (lane == 0) bucket_total[b] = s;
}

// Exclusive scan of NB (<=512) bucket totals -> bucket_base.
__global__ __launch_bounds__(512) void k_scan_nb(
    const int* __restrict__ bucket_total, int* __restrict__ bucket_base, int NB) {
    __shared__ int lds[512];
    const int t = threadIdx.x;
    int v = (t < NB) ? bucket_total[t] : 0;
    lds[t] = v;
    __syncthreads();
    for (int off = 1; off < 512; off <<= 1) {
        int u = (t >= off) ? lds[t - off] : 0;
        __syncthreads();
        lds[t] += u;
        __syncthreads();
    }
    if (t < NB) bucket_base[t] = lds[t] - v;
}

// Wave per bucket: chunked inclusive shuffle-scan down the column, rewriting
// hist[bl][b] into the exact global write base for (block bl, bucket b).
__global__ __launch_bounds__(256) void k_rebase(
    int* __restrict__ hist, const int* __restrict__ bucket_base,
    int NBL, int NB) {
    const int b = blockIdx.x * 4 + (threadIdx.x >> 6);
    if (b >= NB) return;
    const int lane = threadIdx.x & 63;
    int run = bucket_base[b];
    for (int base = 0; base < NBL; base += 64) {
        int bl = base + lane;
        int c = (bl < NBL) ? hist[(size_t)bl * NB + b] : 0;
        int inc = c;
#pragma unroll
        for (int m = 1; m < 64; m <<= 1) {
            int u = __shfl_up(inc, m);
            if (lane >= m) inc += u;
        }
        if (bl < NBL) hist[(size_t)bl * NB + b] = run + (inc - c);
        run += __shfl(inc, 63);
    }
}

// Bin (src,dst) pairs into per-bucket regions of `binned`. LDS cursors are
// seeded with this block's exact global bases -> no global atomics.
__global__ __launch_bounds__(256) void k_bin(
    const int* __restrict__ src, const int* __restrict__ dst,
    const int* __restrict__ hist, int2* __restrict__ binned, int E, int NB) {
    extern __shared__ int lds_pos[];  // NB ints
    const int t = threadIdx.x;
    const int base = blockIdx.x * (256 * BIN_EPT);
    for (int b = t; b < NB; b += 256)
        lds_pos[b] = hist[(size_t)blockIdx.x * NB + b];
    __syncthreads();
#pragma unroll
    for (int j = 0; j < BIN_EPT; ++j) {
        int e = base + j * 256 + t;
        if (e < E) {
            int s = src[e], d = dst[e];
            int pos = atomicAdd(&lds_pos[d >> BKT_SHIFT], 1);
            binned[pos] = make_int2(s, d);
        }
    }
}

// One block per bucket: per-node degree count in LDS, LDS scan ->
// row_start/cnt/dinv, then place csr with LDS cursors.
__global__ __launch_bounds__(256) void k_place(
    const int2* __restrict__ binned, const int* __restrict__ bucket_base,
    int* __restrict__ row_start, int* __restrict__ cnt, float* __restrict__ dinv,
    int* __restrict__ csr, int E, int n, int NB) {
    __shared__ int lcnt[256], sc[256];
    const int b = blockIdx.x;
    const int t = threadIdx.x;
    const int lo = bucket_base[b];
    const int hi = (b + 1 < NB) ? bucket_base[b + 1] : E;
    lcnt[t] = 0;
    __syncthreads();
    for (int i = lo + t; i < hi; i += 256)
        atomicAdd(&lcnt[binned[i].y & 255], 1);
    __syncthreads();
    int c = lcnt[t];
    sc[t] = c;
    __syncthreads();
    for (int off = 1; off < 256; off <<= 1) {
        int u = (t >= off) ? sc[t - off] : 0;
        __syncthreads();
        sc[t] += u;
        __syncthreads();
    }
    int excl = sc[t] - c;
    const int node = (b << BKT_SHIFT) + t;
    if (node < n) {
        row_start[node] = lo + excl;
        cnt[node] = c;
        dinv[node] = rsqrtf((float)c + 1.0f);
    }
    lcnt[t] = excl;  // becomes the local cursor
    __syncthreads();
    for (int i = lo + t; i < hi; i += 256) {
        int2 p = binned[i];
        int r = atomicAdd(&lcnt[p.y & 255], 1);
        csr[lo + r] = p.x;
    }
}

// g1[row][o] = (x[row] @ W1)[o] * dinv[row]
// wave-per-row: lane l covers k in {4l..4l+3} u {256+4l..256+4l+3},
// W fragment in registers, reduce-scatter via shfl_xor.
__global__ __launch_bounds__(256) void k_gemm1(
    const float* __restrict__ x, const float* __restrict__ W1,
    const float* __restrict__ dinv, float* __restrict__ g1, int n) {
    const int lane = threadIdx.x & 63;
    const int wid  = blockIdx.x * (blockDim.x >> 6) + (threadIdx.x >> 6);
    const int nw   = gridDim.x * (blockDim.x >> 6);
    const float4* __restrict__ xv = (const float4*)x;
    const float4* __restrict__ wv = (const float4*)W1;

    float wreg[8][16];
#pragma unroll
    for (int j = 0; j < 4; ++j) {
#pragma unroll
        for (int q = 0; q < 4; ++q) {
            float4 wa = wv[(4 * lane + j) * 4 + q];
            wreg[j][4 * q + 0] = wa.x; wreg[j][4 * q + 1] = wa.y;
            wreg[j][4 * q + 2] = wa.z; wreg[j][4 * q + 3] = wa.w;
            float4 wb = wv[(256 + 4 * lane + j) * 4 + q];
            wreg[4 + j][4 * q + 0] = wb.x; wreg[4 + j][4 * q + 1] = wb.y;
            wreg[4 + j][4 * q + 2] = wb.z; wreg[4 + j][4 * q + 3] = wb.w;
        }
    }

    int row = wid;
    float4 a = make_float4(0.f, 0.f, 0.f, 0.f), b = a;
    if (row < n) { a = xv[row * 128 + lane]; b = xv[row * 128 + 64 + lane]; }
    for (; row < n; row += nw) {
        int nrow = row + nw;
        float4 a2 = a, b2 = b;
        if (nrow < n) { a2 = xv[nrow * 128 + lane]; b2 = xv[nrow * 128 + 64 + lane]; }

        float av[8] = {a.x, a.y, a.z, a.w, b.x, b.y, b.z, b.w};
        float acc[16];
#pragma unroll
        for (int o = 0; o < 16; ++o) acc[o] = 0.f;
#pragma unroll
        for (int j = 0; j < 8; ++j)
#pragma unroll
            for (int o = 0; o < 16; ++o) acc[o] = fmaf(av[j], wreg[j][o], acc[o]);

#pragma unroll
        for (int i = 0; i < 8; ++i) {
            float send = (lane & 32) ? acc[i] : acc[i + 8];
            float recv = __shfl_xor(send, 32);
            float keep = (lane & 32) ? acc[i + 8] : acc[i];
            acc[i] = keep + recv;
        }
#pragma unroll
        for (int i = 0; i < 4; ++i) {
            float send = (lane & 16) ? acc[i] : acc[i + 4];
            float recv = __shfl_xor(send, 16);
            float keep = (lane & 16) ? acc[i + 4] : acc[i];
            acc[i] = keep + recv;
        }
#pragma unroll
        for (int i = 0; i < 2; ++i) {
            float send = (lane & 8) ? acc[i] : acc[i + 2];
            float recv = __shfl_xor(send, 8);
            float keep = (lane & 8) ? acc[i + 2] : acc[i];
            acc[i] = keep + recv;
        }
        {
            float send = (lane & 4) ? acc[0] : acc[1];
            float recv = __shfl_xor(send, 4);
            float keep = (lane & 4) ? acc[1] : acc[0];
            acc[0] = keep + recv;
        }
        float r = acc[0];
        r += __shfl_xor(r, 1);
        r += __shfl_xor(r, 2);
        if ((lane & 3) == 0) g1[(size_t)row * 16 + (lane >> 2)] = r * dinv[row];
        a = a2; b = b2;
    }
}

// Wave per node: gather-sum g1 over CSR neighbors, fuse h2=relu(...), h3=h2@W2,
// g2 = h3*dinv. Lane layout: lane = eo*16 + f (4 edge slots x 16 features).
__global__ __launch_bounds__(256) void k_gather1(
    const int* __restrict__ row_start, const int* __restrict__ cnt,
    const int* __restrict__ csr, const float* __restrict__ g1,
    const float* __restrict__ dinv, const float* __restrict__ W2,
    const float* __restrict__ b1, float* __restrict__ g2, int n) {
    const int wid = blockIdx.x * 4 + (threadIdx.x >> 6);
    if (wid >= n) return;
    const int lane = threadIdx.x & 63;
    const int f = lane & 15, eo = lane >> 4;
    const int base = row_start[wid], deg = cnt[wid];
    float acc = 0.f;
    for (int j = eo; j < deg; j += 4) {
        int s = csr[base + j];
        acc += g1[(size_t)s * 16 + f];
    }
    acc += __shfl_xor(acc, 16);
    acc += __shfl_xor(acc, 32);
    const float dv = dinv[wid];
    float h2 = fmaxf(fmaf(dv, acc + g1[(size_t)wid * 16 + f], b1[f]), 0.f);
    float p0 = h2 * W2[2 * f], p1 = h2 * W2[2 * f + 1];
#pragma unroll
    for (int m = 1; m < 16; m <<= 1) {
        p0 += __shfl_xor(p0, m);
        p1 += __shfl_xor(p1, m);
    }
    if (lane == 0) ((float2*)g2)[wid] = make_float2(p0 * dv, p1 * dv);
}

// Wave per node: gather-sum float2 g2 over CSR neighbors, fuse bias -> out.
__global__ __launch_bounds__(256) void k_gather2(
    const int* __restrict__ row_start, const int* __restrict__ cnt,
    const int* __restrict__ csr, const float* __restrict__ g2,
    const float* __restrict__ dinv, const float* __restrict__ b2,
    float* __restrict__ out, int n) {
    const int wid = blockIdx.x * 4 + (threadIdx.x >> 6);
    if (wid >= n) return;
    const int lane = threadIdx.x & 63;
    const int base = row_start[wid], deg = cnt[wid];
    float a0 = 0.f, a1 = 0.f;
    for (int j = lane; j < deg; j += 64) {
        int s = csr[base + j];
        float2 v = ((const float2*)g2)[s];
        a0 += v.x; a1 += v.y;
    }
#pragma unroll
    for (int m = 1; m < 64; m <<= 1) {
        a0 += __shfl_xor(a0, m);
        a1 += __shfl_xor(a1, m);
    }
    if (lane == 0) {
        float dv = dinv[wid];
        float2 g = ((const float2*)g2)[wid];
        ((float2*)out)[wid] = make_float2(fmaf(dv, a0 + g.x, b2[0]),
                                          fmaf(dv, a1 + g.y, b2[1]));
    }
}

extern "C" void kernel_launch(void* const* d_in, const int* in_sizes, int n_in,
                              void* d_out, int out_size, void* d_ws, size_t ws_size,
                              hipStream_t stream) {
    const float* x  = (const float*)d_in[0];
    const int*   ei = (const int*)d_in[1];
    const float* W1 = (const float*)d_in[2];
    const float* b1 = (const float*)d_in[3];
    const float* W2 = (const float*)d_in[4];
    const float* b2 = (const float*)d_in[5];
    float* out = (float*)d_out;

    const int n = in_sizes[0] / 512;
    const int E = in_sizes[1] / 2;
    const int* src = ei;
    const int* dst = ei + E;

    const int NB = (n + (1 << BKT_SHIFT) - 1) >> BKT_SHIFT;      // buckets (<=512)
    const int nb_bin = (E + 256 * BIN_EPT - 1) / (256 * BIN_EPT); // bin blocks

    char* ws = (char*)d_ws;
    size_t off = 0;
    auto alloc = [&](size_t bytes) {
        char* p = ws + off;
        off += (bytes + 255) & ~(size_t)255;
        return p;
    };
    float* dinv      = (float*)alloc((size_t)n * 4);
    float* g1        = (float*)alloc((size_t)n * 16 * 4);
    float* g2        = (float*)alloc((size_t)n * 2 * 4);
    int*   cnt       = (int*)alloc((size_t)n * 4);
    int*   row_start = (int*)alloc((size_t)n * 4);
    int*   csr       = (int*)alloc((size_t)E * 4);
    int2*  binned    = (int2*)alloc((size_t)E * 8);
    int*   hist         = (int*)alloc((size_t)nb_bin * NB * 4);
    int*   bucket_total = (int*)alloc((size_t)NB * 4);
    int*   bucket_base  = (int*)alloc((size_t)NB * 4);

    const int nb_w = (n + 3) / 4;    // wave-per-node kernels, 4 waves/block
    const int nb_b = (NB + 3) / 4;   // wave-per-bucket kernels, 4 waves/block

    k_bhist<<<nb_bin, 256, NB * 4, stream>>>(dst, hist, E, NB);
    k_colsum<<<nb_b, 256, 0, stream>>>(hist, bucket_total, nb_bin, NB);
    k_scan_nb<<<1, 512, 0, stream>>>(bucket_total, bucket_base, NB);
    k_rebase<<<nb_b, 256, 0, stream>>>(hist, bucket_base, nb_bin, NB);
    k_bin<<<nb_bin, 256, NB * 4, stream>>>(src, dst, hist, binned, E, NB);
    k_place<<<NB, 256, 0, stream>>>(binned, bucket_base, row_start, cnt, dinv, csr, E, n, NB);
    k_gemm1<<<1024, 256, 0, stream>>>(x, W1, dinv, g1, n);
    k_gather1<<<nb_w, 256, 0, stream>>>(row_start, cnt, csr, g1, dinv, W2, b1, g2, n);
    k_gather2<<<nb_w, 256, 0, stream>>>(row_start, cnt, csr, g2, dinv, b2, out, n);
}